// Round 8
// baseline (108.574 us; speedup 1.0000x reference)
//
#include <hip/hip_runtime.h>
#include <hip/hip_bf16.h>
#include <math.h>

// RWKV-6 fused recurrent WKV — chunked linear scan, MFMA formulation.
// B=4, T=2048, H=16, N=64, fp32 in/out; bf16 MFMA operands, fp32 accum.
//
// Chunk TC=64 per workgroup (bh,g), 4 waves, wave w owns t-band [16w,16w+16).
// A[t,s] = sum_i r_t,i k_s,i exp(-(c[t-1]-c[s])), c = incl. prefix of exp(w).
// Dyadic-safe factorization (all staged exponents <= 0):
//   level l pairs (msb(s^t)=l): A-op r*exp(-(c[t-1]-c[b-1])),
//   B-op k*exp(-(c[b-1]-c[s])), b = shared dyadic boundary.
// Levels 0-3 + u-diag: inside 16x16 diagonal tiles (masked accum; level 0
// scales are identically 1). Level 4: tiles (1,0),(3,2). Level 5: (2,0),
// (2,1),(3,0),(3,1). o = R~0 @ S0 + A @ V; L_g = K~end^T @ V -> K2 scan.
//
// R7 lesson: phase 1 was VALU-bound on prep (manual bf16 RNE ~4-5 ops x224,
// redundant level-0 exps) and occupancy-capped by 41KB LDS. Fixes: native
// v_cvt bf16, level-0 = plain r/k, LDS aliasing (sST->sB via reordered
// R~0 GEMM; sAm->sA) -> 25.6KB, 4 blocks/CU.

namespace {
constexpr int B = 4, T = 2048, H = 16, N = 64;
constexpr int BH = B * H;
constexpr int NG = 32;           // chunks per (b,h)
constexpr int TC = 64;           // steps per chunk

typedef __attribute__((ext_vector_type(8))) short s8v;   // 8 bf16
typedef __attribute__((ext_vector_type(4))) float f4v;

#define MFMA16(a, b, c) __builtin_amdgcn_mfma_f32_16x16x32_bf16((a), (b), (c), 0, 0, 0)

__device__ __forceinline__ unsigned short cv(float f) {
    union { __hip_bfloat16 h; unsigned short u; } x;
    x.h = __float2bfloat16(f);        // native v_cvt (RNE), 1 VALU op
    return x.u;
}

// XOR-swizzled element index for [64][64] bf16 LDS tiles (16B-chunk swizzle):
// breaks the 16-way bank conflict of stride-128B ds_read_b128 column slices.
__device__ __forceinline__ int sw(int row, int col) {
    return row * 64 + (col ^ ((row & 7) << 3));
}

// MFMA fragment load: lane l -> row (l&15), k-slice 8*(l>>4); b128 read.
__device__ __forceinline__ s8v frag8(const unsigned short* buf, int row_base, int k_base) {
    const int l = threadIdx.x & 63;
    return *(const s8v*)&buf[sw(row_base + (l & 15), k_base + 8 * (l >> 4))];
}

// ---------------- K1/K3 merged: PHASE 0 = local states, PHASE 1 = outputs ---
template<int PHASE>
__global__ __launch_bounds__(256, 4)
void k13(const float* __restrict__ rp, const float* __restrict__ kp,
         const float* __restrict__ vp, const float* __restrict__ wp,
         const float* __restrict__ up,
         const float* __restrict__ S0g,   // PHASE1: scanned chunk-start states
         float* __restrict__ Lg, float* __restrict__ Ag,   // PHASE0 outputs
         float* __restrict__ out)
{
    __shared__ unsigned short sA[64 * 64];   // staging A-op; aliases sAm (P1)
    __shared__ unsigned short sB[64 * 64];   // staging B-op; aliases sST (P1)
    __shared__ unsigned short sVT[64 * 64];  // V transposed [j][t]
    __shared__ float spans[4 * 64];
    unsigned short* const sST = sB;          // S0^T staged here (read early)
    unsigned short* const sAm = sA;          // A-matrix bf16 [t][s] (late)

    const int blk = blockIdx.x;
    const int g   = blk & (NG - 1);
    const int bh  = blk / NG;
    const int b   = bh / H, h = bh - b * H;
    const int wv  = threadIdx.x >> 6;        // wave 0..3, owns t-band [16wv,+16)
    const int ln  = threadIdx.x & 63;        // lane: i (prep) / frag lane (GEMM)

    const int stride = H * N;
    const int base_w = ((b * T + g * TC + wv * 16) * H + h) * N + ln;
    const int cb = (bh * NG + g) * (N * N);

    // ---- P1: load rows, cum prefix, stage V^T (and S0^T) -------------------
    float ci[16];                            // inclusive prefix of exp(w)
    float k_[16], r_[16];
    {
        float run = 0.f;
#pragma unroll
        for (int tt = 0; tt < 16; ++tt) {
            const int a = base_w + tt * stride;
            run += __expf(wp[a]);
            ci[tt] = run;
            k_[tt] = kp[a];
            if (PHASE == 1) r_[tt] = rp[a];
        }
        spans[wv * 64 + ln] = run;
    }
#pragma unroll
    for (int half = 0; half < 2; ++half) {   // V^T: row j=ln, cols t (own band)
        s8v pk;
#pragma unroll
        for (int e = 0; e < 8; ++e)
            pk[e] = (short)cv(vp[base_w + (half * 8 + e) * stride]);
        *(s8v*)&sVT[sw(ln, wv * 16 + half * 8)] = pk;
    }
    if (PHASE == 1) {
#pragma unroll
        for (int half = 0; half < 2; ++half) {  // S0^T: row j=ln, cols i
            s8v pk;
#pragma unroll
            for (int e = 0; e < 8; ++e)
                pk[e] = (short)cv(S0g[cb + (wv * 16 + half * 8 + e) * 64 + ln]);
            *(s8v*)&sST[sw(ln, wv * 16 + half * 8)] = pk;
        }
    }
    __syncthreads();
    const float sp0 = spans[0 * 64 + ln], sp1 = spans[1 * 64 + ln];
    const float sp2 = spans[2 * 64 + ln], sp3 = spans[3 * 64 + ln];
    const float offW = (wv > 0 ? sp0 : 0.f) + (wv > 1 ? sp1 : 0.f) + (wv > 2 ? sp2 : 0.f);
    const float ctot = sp0 + sp1 + sp2 + sp3;

    if (PHASE == 0) {
        // ---- K~end^T staging into sA as [i=ln][t] --------------------------
        s8v p0, p1;
#pragma unroll
        for (int tt = 0; tt < 16; ++tt) {
            const unsigned short v16 =
                cv(k_[tt] * __expf(-(ctot - (offW + ci[tt]))));
            if (tt < 8) p0[tt] = (short)v16; else p1[tt - 8] = (short)v16;
        }
        *(s8v*)&sA[sw(ln, wv * 16)]     = p0;
        *(s8v*)&sA[sw(ln, wv * 16 + 8)] = p1;
        __syncthreads();
        // ---- L[i][j] = sum_t KT[i][t] V[t][j]; wave owns i-band ------------
#pragma unroll
        for (int jb = 0; jb < 4; ++jb) {
            f4v acc = {0.f, 0.f, 0.f, 0.f};
            acc = MFMA16(frag8(sA, wv * 16, 0),  frag8(sVT, jb * 16, 0),  acc);
            acc = MFMA16(frag8(sA, wv * 16, 32), frag8(sVT, jb * 16, 32), acc);
#pragma unroll
            for (int q = 0; q < 4; ++q) {
                const int i = wv * 16 + (ln >> 4) * 4 + q;
                Lg[cb + i * 64 + jb * 16 + (ln & 15)] = acc[q];
            }
        }
        if (wv == 0) Ag[(bh * NG + g) * 64 + ln] = __expf(-ctot);
        return;
    }

    // ======================= PHASE 1: outputs ==============================
    const float uln = up[h * 64 + ln];
    const int cc = ln & 15;

    // ---- R~0 (chunk-start ref) + O_inter = R~0 @ S0 (frees sST=sB after) ---
#pragma unroll
    for (int tt = 0; tt < 16; ++tt) {
        const float cT = (tt == 0) ? 0.f : ci[tt - 1];
        sA[sw(wv * 16 + tt, ln)] = cv(r_[tt] * __expf(-(offW + cT)));
    }
    f4v accO[4];
#pragma unroll
    for (int jb = 0; jb < 4; ++jb) {
        f4v a = {0.f, 0.f, 0.f, 0.f};
        a = MFMA16(frag8(sA, wv * 16, 0),  frag8(sST, jb * 16, 0),  a);
        a = MFMA16(frag8(sA, wv * 16, 32), frag8(sST, jb * 16, 32), a);
        accO[jb] = a;
    }
    __syncthreads();   // all sST reads done -> sB reusable

    // ---- diag tile (wv,wv): shared plain-k B; level 0 + u-diag + levels 1-3
    f4v accD = {0.f, 0.f, 0.f, 0.f};
#pragma unroll
    for (int tt = 0; tt < 16; ++tt) sB[sw(wv * 16 + tt, ln)] = cv(k_[tt]);
    // level 0: scales identically 1 -> A = plain r
#pragma unroll
    for (int tt = 0; tt < 16; ++tt) sA[sw(wv * 16 + tt, ln)] = cv(r_[tt]);
    {
        f4v tmp = {0.f, 0.f, 0.f, 0.f};
        tmp = MFMA16(frag8(sA, wv * 16, 0),  frag8(sB, wv * 16, 0),  tmp);
        tmp = MFMA16(frag8(sA, wv * 16, 32), frag8(sB, wv * 16, 32), tmp);
#pragma unroll
        for (int q = 0; q < 4; ++q) {
            const int tt = (ln >> 4) * 4 + q;
            if (tt == cc + 1 && (tt & 1)) accD[q] += tmp[q];
        }
    }
    // u-diag: A = r*u, same plain-k B; mask t==s
#pragma unroll
    for (int tt = 0; tt < 16; ++tt) sA[sw(wv * 16 + tt, ln)] = cv(r_[tt] * uln);
    {
        f4v tmp = {0.f, 0.f, 0.f, 0.f};
        tmp = MFMA16(frag8(sA, wv * 16, 0),  frag8(sB, wv * 16, 0),  tmp);
        tmp = MFMA16(frag8(sA, wv * 16, 32), frag8(sB, wv * 16, 32), tmp);
#pragma unroll
        for (int q = 0; q < 4; ++q) {
            const int tt = (ln >> 4) * 4 + q;
            if (tt == cc) accD[q] += tmp[q];
        }
    }
    // levels 1..3: masked dyadic pairs
#pragma unroll
    for (int L = 1; L < 4; ++L) {
#pragma unroll
        for (int tt = 0; tt < 16; ++tt) {
            const int btl = (tt >> L) << L;          // floor boundary (local)
            const int bsl = btl + (1 << L);          // ceil boundary (local)
            const float cT  = (tt == 0) ? 0.f : ci[tt - 1];
            const float cBt = (btl == 0) ? 0.f : ci[btl - 1];
            const float cBs = ci[bsl - 1];
            sA[sw(wv * 16 + tt, ln)] = cv(r_[tt] * __expf(-(cT - cBt)));
            sB[sw(wv * 16 + tt, ln)] = cv(k_[tt] * __expf(-(cBs - ci[tt])));
        }
        f4v tmp = {0.f, 0.f, 0.f, 0.f};
        tmp = MFMA16(frag8(sA, wv * 16, 0),  frag8(sB, wv * 16, 0),  tmp);
        tmp = MFMA16(frag8(sA, wv * 16, 32), frag8(sB, wv * 16, 32), tmp);
#pragma unroll
        for (int q = 0; q < 4; ++q) {
            const int tt = (ln >> 4) * 4 + q;
            if (((tt >> L) == ((cc >> L) + 1)) && (((tt >> L) & 1) != 0))
                accD[q] += tmp[q];
        }
    }

    // ---- level 4: whole tiles (1,0),(3,2); refs = own band start/end -------
#pragma unroll
    for (int tt = 0; tt < 16; ++tt) {
        const float cT = (tt == 0) ? 0.f : ci[tt - 1];
        sA[sw(wv * 16 + tt, ln)] = cv(r_[tt] * __expf(-cT));
        sB[sw(wv * 16 + tt, ln)] = cv(k_[tt] * __expf(-(ci[15] - ci[tt])));
    }
    __syncthreads();
    f4v accL4 = {0.f, 0.f, 0.f, 0.f};
    if (wv == 1 || wv == 3) {
        accL4 = MFMA16(frag8(sA, wv * 16, 0),  frag8(sB, (wv - 1) * 16, 0),  accL4);
        accL4 = MFMA16(frag8(sA, wv * 16, 32), frag8(sB, (wv - 1) * 16, 32), accL4);
    }
    __syncthreads();   // cross-band sB reads done before L5 prep overwrites

    // ---- level 5: tiles (2,0),(2,1),(3,0),(3,1); refs at c[32] -------------
#pragma unroll
    for (int tt = 0; tt < 16; ++tt) {
        if (wv >= 2) {
            const float cT = (tt == 0) ? 0.f : ci[tt - 1];
            const float d  = (wv == 2) ? cT : (cT + sp2);
            sA[sw(wv * 16 + tt, ln)] = cv(r_[tt] * __expf(-d));
        } else {
            const float d = (wv == 0) ? (sp0 + sp1 - ci[tt]) : (sp1 - ci[tt]);
            sB[sw(wv * 16 + tt, ln)] = cv(k_[tt] * __expf(-d));
        }
    }
    __syncthreads();
    f4v acc50 = {0.f, 0.f, 0.f, 0.f}, acc51 = {0.f, 0.f, 0.f, 0.f};
    if (wv >= 2) {
        acc50 = MFMA16(frag8(sA, wv * 16, 0),  frag8(sB, 0, 0),   acc50);
        acc50 = MFMA16(frag8(sA, wv * 16, 32), frag8(sB, 0, 32),  acc50);
        acc51 = MFMA16(frag8(sA, wv * 16, 0),  frag8(sB, 16, 0),  acc51);
        acc51 = MFMA16(frag8(sA, wv * 16, 32), frag8(sB, 16, 32), acc51);
    }

    // ---- materialize A into sAm (=sA alias): all writes are own-band rows;
    //      L5 GEMM read sA rows 32-63 only (own-wave, in-order) -> safe ------
#pragma unroll
    for (int q = 0; q < 4; ++q) {
        const int tt = (ln >> 4) * 4 + q;
        sAm[sw(wv * 16 + tt, wv * 16 + cc)] = cv(accD[q]);
    }
    if (wv == 1 || wv == 3) {
#pragma unroll
        for (int q = 0; q < 4; ++q) {
            const int tt = (ln >> 4) * 4 + q;
            sAm[sw(wv * 16 + tt, (wv - 1) * 16 + cc)] = cv(accL4[q]);
        }
    }
    if (wv >= 2) {
#pragma unroll
        for (int q = 0; q < 4; ++q) {
            const int tt = (ln >> 4) * 4 + q;
            sAm[sw(wv * 16 + tt, cc)]      = cv(acc50[q]);
            sAm[sw(wv * 16 + tt, 16 + cc)] = cv(acc51[q]);
        }
    }
    if (wv == 0 || wv == 2) {    // zero upper-adjacent tile for K32 pairing
#pragma unroll
        for (int q = 0; q < 4; ++q) {
            const int tt = (ln >> 4) * 4 + q;
            sAm[sw(wv * 16 + tt, (wv + 1) * 16 + cc)] = 0;
        }
    }

    // ---- out = accO + A @ V (A-op: own rows; B-op: sVT stable since P1) ----
#pragma unroll
    for (int jb = 0; jb < 4; ++jb) {
        f4v a = accO[jb];
        a = MFMA16(frag8(sAm, wv * 16, 0), frag8(sVT, jb * 16, 0), a);
        if (wv >= 2)
            a = MFMA16(frag8(sAm, wv * 16, 32), frag8(sVT, jb * 16, 32), a);
#pragma unroll
        for (int q = 0; q < 4; ++q) {
            const int t = g * TC + wv * 16 + (ln >> 4) * 4 + q;
            out[((b * T + t) * H + h) * N + jb * 16 + (ln & 15)] = a[q];
        }
    }
}

// ---------------- K2: inter-chunk scan, in place (L -> S0), float4 ----------
__global__ __launch_bounds__(256)
void k2_scan(float* __restrict__ L, const float* __restrict__ A)
{
    const int tid = blockIdx.x * 256 + threadIdx.x;
    const int j4 = tid & (N / 4 - 1);
    const int i  = (tid >> 4) & (N - 1);
    const int bh = tid >> 10;

    float4* L4 = (float4*)L;
    const int lstride = N * N / 4;
    int lidx = bh * NG * lstride + i * (N / 4) + j4;
    int aidx = bh * NG * N + i;

    float4 S = make_float4(0.f, 0.f, 0.f, 0.f);
    for (int g = 0; g < NG; ++g) {
        const float4 l = L4[lidx];
        const float  a = A[aidx];
        L4[lidx] = S;
        S.x = fmaf(a, S.x, l.x);
        S.y = fmaf(a, S.y, l.y);
        S.z = fmaf(a, S.z, l.z);
        S.w = fmaf(a, S.w, l.w);
        lidx += lstride;
        aidx += N;
    }
}

// ---------------- no-workspace fallback: sequential per (b,h) ---------------
__global__ __launch_bounds__(64, 2)
void k_seq(const float* __restrict__ rp, const float* __restrict__ kp,
           const float* __restrict__ vp, const float* __restrict__ wp,
           const float* __restrict__ up, float* __restrict__ out)
{
    const int bh = blockIdx.x;
    const int b = bh / H, h = bh - b * H;
    const int j = threadIdx.x;

    float S[N];
#pragma unroll
    for (int i = 0; i < N; ++i) S[i] = 0.f;

    const int stride = H * N;
    int base = ((b * T) * H + h) * N;
    const int ubase = h * N;

#pragma unroll 1
    for (int tt = 0; tt < T; ++tt) {
        const float vj = vp[base + j];
        const int row = base;
        float sr = 0.f, o0 = 0.f, o1 = 0.f;
#pragma unroll
        for (int i = 0; i < N; ++i) {
            const float ki = kp[row + i];
            const float di = __expf(-__expf(wp[row + i]));
            const float ri = rp[row + i];
            sr = fmaf(ri * up[ubase + i], ki, sr);
            if (i & 1) o1 = fmaf(ri, S[i], o1);
            else       o0 = fmaf(ri, S[i], o0);
            S[i] = fmaf(di, S[i], ki * vj);
        }
        out[base + j] = fmaf(sr, vj, o0 + o1);
        base += stride;
    }
}

} // anon namespace

extern "C" void kernel_launch(void* const* d_in, const int* in_sizes, int n_in,
                              void* d_out, int out_size, void* d_ws, size_t ws_size,
                              hipStream_t stream)
{
    const float* r = (const float*)d_in[0];
    const float* k = (const float*)d_in[1];
    const float* v = (const float*)d_in[2];
    const float* w = (const float*)d_in[3];
    const float* u = (const float*)d_in[4];
    float* out = (float*)d_out;

    const size_t l_elems = (size_t)BH * NG * N * N;   // 8,388,608
    const size_t a_elems = (size_t)BH * NG * N;       // 131,072
    const size_t ws_need = (l_elems + a_elems) * sizeof(float);  // ~34 MB

    if (ws_size >= ws_need) {
        float* L = (float*)d_ws;
        float* A = L + l_elems;
        k13<0><<<BH * NG, 256, 0, stream>>>(r, k, v, w, u, nullptr, L, A, nullptr);
        k2_scan<<<(BH * N * N / 4) / 256, 256, 0, stream>>>(L, A);
        k13<1><<<BH * NG, 256, 0, stream>>>(r, k, v, w, u, L, nullptr, nullptr, out);
    } else {
        k_seq<<<BH, 64, 0, stream>>>(r, k, v, w, u, out);
    }
}

// Round 9
// 81.492 us; speedup vs baseline: 1.3323x; 1.3323x over previous
//
#include <hip/hip_runtime.h>
#include <hip/hip_bf16.h>
#include <math.h>

// RWKV-6 fused recurrent WKV — chunked linear scan, MFMA formulation.
// B=4, T=2048, H=16, N=64, fp32 in/out; bf16 MFMA operands, fp32 accum.
//
// Chunk TC=64 per workgroup (bh,g), 4 waves, wave w owns t-band [16w,16w+16).
// A[t,s] = sum_i r_t,i k_s,i exp(-(c[t-1]-c[s])), c = incl. prefix of exp(w).
// Dyadic-safe factorization (all staged exponents <= 0):
//   level l pairs (msb(s^t)=l): A-op r*exp(-(c[t-1]-c[b-1])),
//   B-op k*exp(-(c[b-1]-c[s])), b = shared dyadic boundary.
// Levels 0-3 + u-diag: inside 16x16 diagonal tiles (masked accum; level-0
// scales are identically 1; u-diag shares the plain-k B tile). Level 4:
// tiles (1,0),(3,2). Level 5: (2,0),(2,1),(3,0),(3,1).
// o = R~0 @ S0 + A @ V;  L_g = K~end^T @ V -> K2 scan.
//
// R8 lesson (3rd register-file burn): moving the R~0@S0 GEMM to the front
// (to alias sST->sB) made accO[4]+r_/k_/ci live across the whole kernel ->
// ~98MB scratch spill (WRITE 131MB, VGPR split 64). NEVER trade register
// live-range for LDS. R9 = R7 ordering (accO last, short-lived) + R8's cv()
// and level-0/u-diag sharing + sAm->sA alias only (33.8KB LDS, 4 blocks/CU).

namespace {
constexpr int B = 4, T = 2048, H = 16, N = 64;
constexpr int BH = B * H;
constexpr int NG = 32;           // chunks per (b,h)
constexpr int TC = 64;           // steps per chunk

typedef __attribute__((ext_vector_type(8))) short s8v;   // 8 bf16
typedef __attribute__((ext_vector_type(4))) float f4v;

#define MFMA16(a, b, c) __builtin_amdgcn_mfma_f32_16x16x32_bf16((a), (b), (c), 0, 0, 0)

__device__ __forceinline__ unsigned short cv(float f) {
    union { __hip_bfloat16 h; unsigned short u; } x;
    x.h = __float2bfloat16(f);        // native v_cvt (RNE), 1 VALU op
    return x.u;
}

// XOR-swizzled element index for [64][64] bf16 LDS tiles (16B-chunk swizzle):
// breaks the 16-way bank conflict of stride-128B ds_read_b128 column slices.
__device__ __forceinline__ int sw(int row, int col) {
    return row * 64 + (col ^ ((row & 7) << 3));
}

// MFMA fragment load: lane l -> row (l&15), k-slice 8*(l>>4); b128 read.
__device__ __forceinline__ s8v frag8(const unsigned short* buf, int row_base, int k_base) {
    const int l = threadIdx.x & 63;
    return *(const s8v*)&buf[sw(row_base + (l & 15), k_base + 8 * (l >> 4))];
}

// ---------------- K1/K3 merged: PHASE 0 = local states, PHASE 1 = outputs ---
template<int PHASE>
__global__ __launch_bounds__(256, 4)
void k13(const float* __restrict__ rp, const float* __restrict__ kp,
         const float* __restrict__ vp, const float* __restrict__ wp,
         const float* __restrict__ up,
         const float* __restrict__ S0g,   // PHASE1: scanned chunk-start states
         float* __restrict__ Lg, float* __restrict__ Ag,   // PHASE0 outputs
         float* __restrict__ out)
{
    __shared__ unsigned short sA[64 * 64];   // staging A-op; aliases sAm (late)
    __shared__ unsigned short sB[64 * 64];   // staging B-op
    __shared__ unsigned short sVT[64 * 64];  // V transposed [j][t]
    __shared__ unsigned short sST[64 * 64];  // S0 transposed [j][i] (PHASE1)
    __shared__ float spans[4 * 64];
    unsigned short* const sAm = sA;          // A-matrix bf16 [t][s] (late alias)

    const int blk = blockIdx.x;
    const int g   = blk & (NG - 1);
    const int bh  = blk / NG;
    const int b   = bh / H, h = bh - b * H;
    const int wv  = threadIdx.x >> 6;        // wave 0..3, owns t-band [16wv,+16)
    const int ln  = threadIdx.x & 63;        // lane: i (prep) / frag lane (GEMM)

    const int stride = H * N;
    const int base_w = ((b * T + g * TC + wv * 16) * H + h) * N + ln;
    const int cb = (bh * NG + g) * (N * N);

    // ---- P1: load rows, cum prefix, stage V^T (and S0^T) -------------------
    float ci[16];                            // inclusive prefix of exp(w)
    float k_[16], r_[16];
    {
        float run = 0.f;
#pragma unroll
        for (int tt = 0; tt < 16; ++tt) {
            const int a = base_w + tt * stride;
            run += __expf(wp[a]);
            ci[tt] = run;
            k_[tt] = kp[a];
            if (PHASE == 1) r_[tt] = rp[a];
        }
        spans[wv * 64 + ln] = run;
    }
#pragma unroll
    for (int half = 0; half < 2; ++half) {   // V^T: row j=ln, cols t (own band)
        s8v pk;
#pragma unroll
        for (int e = 0; e < 8; ++e)
            pk[e] = (short)cv(vp[base_w + (half * 8 + e) * stride]);
        *(s8v*)&sVT[sw(ln, wv * 16 + half * 8)] = pk;
    }
    if (PHASE == 1) {
#pragma unroll
        for (int half = 0; half < 2; ++half) {  // S0^T: row j=ln, cols i
            s8v pk;
#pragma unroll
            for (int e = 0; e < 8; ++e)
                pk[e] = (short)cv(S0g[cb + (wv * 16 + half * 8 + e) * 64 + ln]);
            *(s8v*)&sST[sw(ln, wv * 16 + half * 8)] = pk;
        }
    }
    __syncthreads();
    const float sp0 = spans[0 * 64 + ln], sp1 = spans[1 * 64 + ln];
    const float sp2 = spans[2 * 64 + ln], sp3 = spans[3 * 64 + ln];
    const float offW = (wv > 0 ? sp0 : 0.f) + (wv > 1 ? sp1 : 0.f) + (wv > 2 ? sp2 : 0.f);
    const float ctot = sp0 + sp1 + sp2 + sp3;

    if (PHASE == 0) {
        // ---- K~end^T staging into sA as [i=ln][t] --------------------------
        s8v p0, p1;
#pragma unroll
        for (int tt = 0; tt < 16; ++tt) {
            const unsigned short v16 =
                cv(k_[tt] * __expf(-(ctot - (offW + ci[tt]))));
            if (tt < 8) p0[tt] = (short)v16; else p1[tt - 8] = (short)v16;
        }
        *(s8v*)&sA[sw(ln, wv * 16)]     = p0;
        *(s8v*)&sA[sw(ln, wv * 16 + 8)] = p1;
        __syncthreads();
        // ---- L[i][j] = sum_t KT[i][t] V[t][j]; wave owns i-band ------------
#pragma unroll
        for (int jb = 0; jb < 4; ++jb) {
            f4v acc = {0.f, 0.f, 0.f, 0.f};
            acc = MFMA16(frag8(sA, wv * 16, 0),  frag8(sVT, jb * 16, 0),  acc);
            acc = MFMA16(frag8(sA, wv * 16, 32), frag8(sVT, jb * 16, 32), acc);
#pragma unroll
            for (int q = 0; q < 4; ++q) {
                const int i = wv * 16 + (ln >> 4) * 4 + q;
                Lg[cb + i * 64 + jb * 16 + (ln & 15)] = acc[q];
            }
        }
        if (wv == 0) Ag[(bh * NG + g) * 64 + ln] = __expf(-ctot);
        return;
    }

    // ======================= PHASE 1: outputs ==============================
    const float uln = up[h * 64 + ln];
    const int cc = ln & 15;

    // ---- diag tile (wv,wv): shared plain-k B; level 0 + u-diag + levels 1-3
    // (A-op and B-op both own-band rows -> wave-local, no barriers)
    f4v accD = {0.f, 0.f, 0.f, 0.f};
#pragma unroll
    for (int tt = 0; tt < 16; ++tt) sB[sw(wv * 16 + tt, ln)] = cv(k_[tt]);
    // level 0: scales identically 1 -> A = plain r
#pragma unroll
    for (int tt = 0; tt < 16; ++tt) sA[sw(wv * 16 + tt, ln)] = cv(r_[tt]);
    {
        f4v tmp = {0.f, 0.f, 0.f, 0.f};
        tmp = MFMA16(frag8(sA, wv * 16, 0),  frag8(sB, wv * 16, 0),  tmp);
        tmp = MFMA16(frag8(sA, wv * 16, 32), frag8(sB, wv * 16, 32), tmp);
#pragma unroll
        for (int q = 0; q < 4; ++q) {
            const int tt = (ln >> 4) * 4 + q;
            if (tt == cc + 1 && (tt & 1)) accD[q] += tmp[q];
        }
    }
    // u-diag: A = r*u, same plain-k B; mask t==s
#pragma unroll
    for (int tt = 0; tt < 16; ++tt) sA[sw(wv * 16 + tt, ln)] = cv(r_[tt] * uln);
    {
        f4v tmp = {0.f, 0.f, 0.f, 0.f};
        tmp = MFMA16(frag8(sA, wv * 16, 0),  frag8(sB, wv * 16, 0),  tmp);
        tmp = MFMA16(frag8(sA, wv * 16, 32), frag8(sB, wv * 16, 32), tmp);
#pragma unroll
        for (int q = 0; q < 4; ++q) {
            const int tt = (ln >> 4) * 4 + q;
            if (tt == cc) accD[q] += tmp[q];
        }
    }
    // levels 1..3: masked dyadic pairs
#pragma unroll
    for (int L = 1; L < 4; ++L) {
#pragma unroll
        for (int tt = 0; tt < 16; ++tt) {
            const int btl = (tt >> L) << L;          // floor boundary (local)
            const int bsl = btl + (1 << L);          // ceil boundary (local)
            const float cT  = (tt == 0) ? 0.f : ci[tt - 1];
            const float cBt = (btl == 0) ? 0.f : ci[btl - 1];
            const float cBs = ci[bsl - 1];
            sA[sw(wv * 16 + tt, ln)] = cv(r_[tt] * __expf(-(cT - cBt)));
            sB[sw(wv * 16 + tt, ln)] = cv(k_[tt] * __expf(-(cBs - ci[tt])));
        }
        f4v tmp = {0.f, 0.f, 0.f, 0.f};
        tmp = MFMA16(frag8(sA, wv * 16, 0),  frag8(sB, wv * 16, 0),  tmp);
        tmp = MFMA16(frag8(sA, wv * 16, 32), frag8(sB, wv * 16, 32), tmp);
#pragma unroll
        for (int q = 0; q < 4; ++q) {
            const int tt = (ln >> 4) * 4 + q;
            if (((tt >> L) == ((cc >> L) + 1)) && (((tt >> L) & 1) != 0))
                accD[q] += tmp[q];
        }
    }

    // ---- level 4: whole tiles (1,0),(3,2); refs = own band start/end -------
#pragma unroll
    for (int tt = 0; tt < 16; ++tt) {
        const float cT = (tt == 0) ? 0.f : ci[tt - 1];
        sA[sw(wv * 16 + tt, ln)] = cv(r_[tt] * __expf(-cT));
        sB[sw(wv * 16 + tt, ln)] = cv(k_[tt] * __expf(-(ci[15] - ci[tt])));
    }
    __syncthreads();
    f4v accL4 = {0.f, 0.f, 0.f, 0.f};
    if (wv == 1 || wv == 3) {
        accL4 = MFMA16(frag8(sA, wv * 16, 0),  frag8(sB, (wv - 1) * 16, 0),  accL4);
        accL4 = MFMA16(frag8(sA, wv * 16, 32), frag8(sB, (wv - 1) * 16, 32), accL4);
    }
    __syncthreads();   // cross-band sB reads done before L5 prep overwrites

    // ---- level 5: tiles (2,0),(2,1),(3,0),(3,1); refs at c[32] -------------
#pragma unroll
    for (int tt = 0; tt < 16; ++tt) {
        if (wv >= 2) {
            const float cT = (tt == 0) ? 0.f : ci[tt - 1];
            const float d  = (wv == 2) ? cT : (cT + sp2);
            sA[sw(wv * 16 + tt, ln)] = cv(r_[tt] * __expf(-d));
        } else {
            const float d = (wv == 0) ? (sp0 + sp1 - ci[tt]) : (sp1 - ci[tt]);
            sB[sw(wv * 16 + tt, ln)] = cv(k_[tt] * __expf(-d));
        }
    }
    __syncthreads();
    f4v acc50 = {0.f, 0.f, 0.f, 0.f}, acc51 = {0.f, 0.f, 0.f, 0.f};
    if (wv >= 2) {
        acc50 = MFMA16(frag8(sA, wv * 16, 0),  frag8(sB, 0, 0),   acc50);
        acc50 = MFMA16(frag8(sA, wv * 16, 32), frag8(sB, 0, 32),  acc50);
        acc51 = MFMA16(frag8(sA, wv * 16, 0),  frag8(sB, 16, 0),  acc51);
        acc51 = MFMA16(frag8(sA, wv * 16, 32), frag8(sB, 16, 32), acc51);
    }
    // (no barrier: R~0 prep below writes only own sA rows; L5 GEMM read own
    //  sA rows in-order and sB bands 0/1, which are not rewritten)

    // ---- R~0 (chunk-start ref) + O_inter = R~0 @ S0 (accO short-lived!) ----
#pragma unroll
    for (int tt = 0; tt < 16; ++tt) {
        const float cT = (tt == 0) ? 0.f : ci[tt - 1];
        sA[sw(wv * 16 + tt, ln)] = cv(r_[tt] * __expf(-(offW + cT)));
    }
    f4v accO[4];
#pragma unroll
    for (int jb = 0; jb < 4; ++jb) {
        f4v a = {0.f, 0.f, 0.f, 0.f};
        a = MFMA16(frag8(sA, wv * 16, 0),  frag8(sST, jb * 16, 0),  a);
        a = MFMA16(frag8(sA, wv * 16, 32), frag8(sST, jb * 16, 32), a);
        accO[jb] = a;
    }

    // ---- materialize A into sAm (=sA alias): own-band rows only, after the
    //      last own-row sA read (accO GEMM, wave-in-order) -> safe -----------
#pragma unroll
    for (int q = 0; q < 4; ++q) {
        const int tt = (ln >> 4) * 4 + q;
        sAm[sw(wv * 16 + tt, wv * 16 + cc)] = cv(accD[q]);
    }
    if (wv == 1 || wv == 3) {
#pragma unroll
        for (int q = 0; q < 4; ++q) {
            const int tt = (ln >> 4) * 4 + q;
            sAm[sw(wv * 16 + tt, (wv - 1) * 16 + cc)] = cv(accL4[q]);
        }
    }
    if (wv >= 2) {
#pragma unroll
        for (int q = 0; q < 4; ++q) {
            const int tt = (ln >> 4) * 4 + q;
            sAm[sw(wv * 16 + tt, cc)]      = cv(acc50[q]);
            sAm[sw(wv * 16 + tt, 16 + cc)] = cv(acc51[q]);
        }
    }
    if (wv == 0 || wv == 2) {    // zero upper-adjacent tile for K32 pairing
#pragma unroll
        for (int q = 0; q < 4; ++q) {
            const int tt = (ln >> 4) * 4 + q;
            sAm[sw(wv * 16 + tt, (wv + 1) * 16 + cc)] = 0;
        }
    }

    // ---- out = accO + A @ V (A-op: own rows; B-op: sVT stable since P1) ----
#pragma unroll
    for (int jb = 0; jb < 4; ++jb) {
        f4v a = accO[jb];
        a = MFMA16(frag8(sAm, wv * 16, 0), frag8(sVT, jb * 16, 0), a);
        if (wv >= 2)
            a = MFMA16(frag8(sAm, wv * 16, 32), frag8(sVT, jb * 16, 32), a);
#pragma unroll
        for (int q = 0; q < 4; ++q) {
            const int t = g * TC + wv * 16 + (ln >> 4) * 4 + q;
            out[((b * T + t) * H + h) * N + jb * 16 + (ln & 15)] = a[q];
        }
    }
}

// ---------------- K2: inter-chunk scan, in place (L -> S0), float4 ----------
__global__ __launch_bounds__(256)
void k2_scan(float* __restrict__ L, const float* __restrict__ A)
{
    const int tid = blockIdx.x * 256 + threadIdx.x;
    const int j4 = tid & (N / 4 - 1);
    const int i  = (tid >> 4) & (N - 1);
    const int bh = tid >> 10;

    float4* L4 = (float4*)L;
    const int lstride = N * N / 4;
    int lidx = bh * NG * lstride + i * (N / 4) + j4;
    int aidx = bh * NG * N + i;

    float4 S = make_float4(0.f, 0.f, 0.f, 0.f);
    for (int g = 0; g < NG; ++g) {
        const float4 l = L4[lidx];
        const float  a = A[aidx];
        L4[lidx] = S;
        S.x = fmaf(a, S.x, l.x);
        S.y = fmaf(a, S.y, l.y);
        S.z = fmaf(a, S.z, l.z);
        S.w = fmaf(a, S.w, l.w);
        lidx += lstride;
        aidx += N;
    }
}

// ---------------- no-workspace fallback: sequential per (b,h) ---------------
__global__ __launch_bounds__(64, 2)
void k_seq(const float* __restrict__ rp, const float* __restrict__ kp,
           const float* __restrict__ vp, const float* __restrict__ wp,
           const float* __restrict__ up, float* __restrict__ out)
{
    const int bh = blockIdx.x;
    const int b = bh / H, h = bh - b * H;
    const int j = threadIdx.x;

    float S[N];
#pragma unroll
    for (int i = 0; i < N; ++i) S[i] = 0.f;

    const int stride = H * N;
    int base = ((b * T) * H + h) * N;
    const int ubase = h * N;

#pragma unroll 1
    for (int tt = 0; tt < T; ++tt) {
        const float vj = vp[base + j];
        const int row = base;
        float sr = 0.f, o0 = 0.f, o1 = 0.f;
#pragma unroll
        for (int i = 0; i < N; ++i) {
            const float ki = kp[row + i];
            const float di = __expf(-__expf(wp[row + i]));
            const float ri = rp[row + i];
            sr = fmaf(ri * up[ubase + i], ki, sr);
            if (i & 1) o1 = fmaf(ri, S[i], o1);
            else       o0 = fmaf(ri, S[i], o0);
            S[i] = fmaf(di, S[i], ki * vj);
        }
        out[base + j] = fmaf(sr, vj, o0 + o1);
        base += stride;
    }
}

} // anon namespace

extern "C" void kernel_launch(void* const* d_in, const int* in_sizes, int n_in,
                              void* d_out, int out_size, void* d_ws, size_t ws_size,
                              hipStream_t stream)
{
    const float* r = (const float*)d_in[0];
    const float* k = (const float*)d_in[1];
    const float* v = (const float*)d_in[2];
    const float* w = (const float*)d_in[3];
    const float* u = (const float*)d_in[4];
    float* out = (float*)d_out;

    const size_t l_elems = (size_t)BH * NG * N * N;   // 8,388,608
    const size_t a_elems = (size_t)BH * NG * N;       // 131,072
    const size_t ws_need = (l_elems + a_elems) * sizeof(float);  // ~34 MB

    if (ws_size >= ws_need) {
        float* L = (float*)d_ws;
        float* A = L + l_elems;
        k13<0><<<BH * NG, 256, 0, stream>>>(r, k, v, w, u, nullptr, L, A, nullptr);
        k2_scan<<<(BH * N * N / 4) / 256, 256, 0, stream>>>(L, A);
        k13<1><<<BH * NG, 256, 0, stream>>>(r, k, v, w, u, L, nullptr, nullptr, out);
    } else {
        k_seq<<<BH, 64, 0, stream>>>(r, k, v, w, u, out);
    }
}

// Round 10
// 74.308 us; speedup vs baseline: 1.4611x; 1.0967x over previous
//
#include <hip/hip_runtime.h>
#include <math.h>

// RWKV-6 fused recurrent WKV — chunked linear scan, MFMA formulation.
// B=4, T=2048, H=16, N=64, fp32 in/out; bf16 MFMA operands, fp32 accum.
//
// Chunk TC=64 per workgroup (bh,g), 4 waves, wave w owns t-band [16w,16w+16).
// A[t,s] = sum_i r_t,i k_s,i exp(-(c[t-1]-c[s])), c = incl. prefix of exp(w).
// Dyadic-safe factorization (all staged exponents <= 0):
//   level l pairs (msb(s^t)=l): A-op r*exp(-(c[t-1]-c[b-1])),
//   B-op k*exp(-(c[b-1]-c[s])), b = shared dyadic boundary.
// Levels 0-3 + u-diag: inside 16x16 diagonal tiles (masked accum; level-0
// scales are identically 1; u-diag shares the plain-k B tile). Level 4:
// tiles (1,0),(3,2). Level 5: (2,0),(2,1),(3,0),(3,1).
// o = R~0 @ S0 + A @ V;  L_g = K~end^T @ V -> K2 scan.
//
// R8 lesson: never trade register live-range for LDS (accO must stay last).
// R9 lesson (4th register burn): __float2bfloat16's NaN-select chains tip
//   regalloc into spill at the 128-reg budget (VGPR 84->64, +28MB scratch).
//   Manual branchless RNE is codegen-stable. KEEP IT.
// R10: +8-pad LDS tiles [64][72] instead of XOR swizzle: staging-write
//   addresses affine in row (strength-reduced), frag reads 2-way bank
//   aliased (free, m136). Cuts ~900 addr-VALU ops/wave.

namespace {
constexpr int B = 4, T = 2048, H = 16, N = 64;
constexpr int BH = B * H;
constexpr int NG = 32;           // chunks per (b,h)
constexpr int TC = 64;           // steps per chunk
constexpr int LDP = 72;          // padded LDS row stride (elems): 144B, 16B-aligned

typedef __attribute__((ext_vector_type(8))) short s8v;   // 8 bf16
typedef __attribute__((ext_vector_type(4))) float f4v;

#define MFMA16(a, b, c) __builtin_amdgcn_mfma_f32_16x16x32_bf16((a), (b), (c), 0, 0, 0)

__device__ __forceinline__ unsigned short cv(float f) {
    union { float f; unsigned u; } x; x.f = f;
    unsigned r = x.u + 0x7FFFu + ((x.u >> 16) & 1u);   // branchless RNE
    return (unsigned short)(r >> 16);
}

// Padded element index: row*72 + col. Affine in row (no xor recompute).
__device__ __forceinline__ int sw(int row, int col) {
    return row * LDP + col;
}

// MFMA fragment load: lane l -> row (l&15), k-slice 8*(l>>4); b128 read.
__device__ __forceinline__ s8v frag8(const unsigned short* buf, int row_base, int k_base) {
    const int l = threadIdx.x & 63;
    return *(const s8v*)&buf[sw(row_base + (l & 15), k_base + 8 * (l >> 4))];
}

// ---------------- K1/K3 merged: PHASE 0 = local states, PHASE 1 = outputs ---
template<int PHASE>
__global__ __launch_bounds__(256, 4)
void k13(const float* __restrict__ rp, const float* __restrict__ kp,
         const float* __restrict__ vp, const float* __restrict__ wp,
         const float* __restrict__ up,
         const float* __restrict__ S0g,   // PHASE1: scanned chunk-start states
         float* __restrict__ Lg, float* __restrict__ Ag,   // PHASE0 outputs
         float* __restrict__ out)
{
    __shared__ unsigned short sA[64 * LDP];   // staging A-op; aliases sAm (late)
    __shared__ unsigned short sB[64 * LDP];   // staging B-op
    __shared__ unsigned short sVT[64 * LDP];  // V transposed [j][t]
    __shared__ unsigned short sST[64 * LDP];  // S0 transposed [j][i] (PHASE1)
    __shared__ float spans[4 * 64];
    unsigned short* const sAm = sA;           // A-matrix bf16 [t][s] (late alias)

    const int blk = blockIdx.x;
    const int g   = blk & (NG - 1);
    const int bh  = blk / NG;
    const int b   = bh / H, h = bh - b * H;
    const int wv  = threadIdx.x >> 6;        // wave 0..3, owns t-band [16wv,+16)
    const int ln  = threadIdx.x & 63;        // lane: i (prep) / frag lane (GEMM)

    const int stride = H * N;
    const int base_w = ((b * T + g * TC + wv * 16) * H + h) * N + ln;
    const int cb = (bh * NG + g) * (N * N);

    // ---- P1: load rows, cum prefix, stage V^T (and S0^T) -------------------
    float ci[16];                            // inclusive prefix of exp(w)
    float k_[16], r_[16];
    {
        float run = 0.f;
#pragma unroll
        for (int tt = 0; tt < 16; ++tt) {
            const int a = base_w + tt * stride;
            run += __expf(wp[a]);
            ci[tt] = run;
            k_[tt] = kp[a];
            if (PHASE == 1) r_[tt] = rp[a];
        }
        spans[wv * 64 + ln] = run;
    }
#pragma unroll
    for (int half = 0; half < 2; ++half) {   // V^T: row j=ln, cols t (own band)
        s8v pk;
#pragma unroll
        for (int e = 0; e < 8; ++e)
            pk[e] = (short)cv(vp[base_w + (half * 8 + e) * stride]);
        *(s8v*)&sVT[sw(ln, wv * 16 + half * 8)] = pk;
    }
    if (PHASE == 1) {
#pragma unroll
        for (int half = 0; half < 2; ++half) {  // S0^T: row j=ln, cols i
            s8v pk;
#pragma unroll
            for (int e = 0; e < 8; ++e)
                pk[e] = (short)cv(S0g[cb + (wv * 16 + half * 8 + e) * 64 + ln]);
            *(s8v*)&sST[sw(ln, wv * 16 + half * 8)] = pk;
        }
    }
    __syncthreads();
    const float sp0 = spans[0 * 64 + ln], sp1 = spans[1 * 64 + ln];
    const float sp2 = spans[2 * 64 + ln], sp3 = spans[3 * 64 + ln];
    const float offW = (wv > 0 ? sp0 : 0.f) + (wv > 1 ? sp1 : 0.f) + (wv > 2 ? sp2 : 0.f);
    const float ctot = sp0 + sp1 + sp2 + sp3;

    if (PHASE == 0) {
        // ---- K~end^T staging into sA as [i=ln][t] --------------------------
        s8v p0, p1;
#pragma unroll
        for (int tt = 0; tt < 16; ++tt) {
            const unsigned short v16 =
                cv(k_[tt] * __expf(-(ctot - (offW + ci[tt]))));
            if (tt < 8) p0[tt] = (short)v16; else p1[tt - 8] = (short)v16;
        }
        *(s8v*)&sA[sw(ln, wv * 16)]     = p0;
        *(s8v*)&sA[sw(ln, wv * 16 + 8)] = p1;
        __syncthreads();
        // ---- L[i][j] = sum_t KT[i][t] V[t][j]; wave owns i-band ------------
#pragma unroll
        for (int jb = 0; jb < 4; ++jb) {
            f4v acc = {0.f, 0.f, 0.f, 0.f};
            acc = MFMA16(frag8(sA, wv * 16, 0),  frag8(sVT, jb * 16, 0),  acc);
            acc = MFMA16(frag8(sA, wv * 16, 32), frag8(sVT, jb * 16, 32), acc);
#pragma unroll
            for (int q = 0; q < 4; ++q) {
                const int i = wv * 16 + (ln >> 4) * 4 + q;
                Lg[cb + i * 64 + jb * 16 + (ln & 15)] = acc[q];
            }
        }
        if (wv == 0) Ag[(bh * NG + g) * 64 + ln] = __expf(-ctot);
        return;
    }

    // ======================= PHASE 1: outputs ==============================
    const float uln = up[h * 64 + ln];
    const int cc = ln & 15;

    // ---- diag tile (wv,wv): shared plain-k B; level 0 + u-diag + levels 1-3
    // (A-op and B-op both own-band rows -> wave-local, no barriers)
    f4v accD = {0.f, 0.f, 0.f, 0.f};
#pragma unroll
    for (int tt = 0; tt < 16; ++tt) sB[sw(wv * 16 + tt, ln)] = cv(k_[tt]);
    // level 0: scales identically 1 -> A = plain r
#pragma unroll
    for (int tt = 0; tt < 16; ++tt) sA[sw(wv * 16 + tt, ln)] = cv(r_[tt]);
    {
        f4v tmp = {0.f, 0.f, 0.f, 0.f};
        tmp = MFMA16(frag8(sA, wv * 16, 0),  frag8(sB, wv * 16, 0),  tmp);
        tmp = MFMA16(frag8(sA, wv * 16, 32), frag8(sB, wv * 16, 32), tmp);
#pragma unroll
        for (int q = 0; q < 4; ++q) {
            const int tt = (ln >> 4) * 4 + q;
            if (tt == cc + 1 && (tt & 1)) accD[q] += tmp[q];
        }
    }
    // u-diag: A = r*u, same plain-k B; mask t==s
#pragma unroll
    for (int tt = 0; tt < 16; ++tt) sA[sw(wv * 16 + tt, ln)] = cv(r_[tt] * uln);
    {
        f4v tmp = {0.f, 0.f, 0.f, 0.f};
        tmp = MFMA16(frag8(sA, wv * 16, 0),  frag8(sB, wv * 16, 0),  tmp);
        tmp = MFMA16(frag8(sA, wv * 16, 32), frag8(sB, wv * 16, 32), tmp);
#pragma unroll
        for (int q = 0; q < 4; ++q) {
            const int tt = (ln >> 4) * 4 + q;
            if (tt == cc) accD[q] += tmp[q];
        }
    }
    // levels 1..3: masked dyadic pairs
#pragma unroll
    for (int L = 1; L < 4; ++L) {
#pragma unroll
        for (int tt = 0; tt < 16; ++tt) {
            const int btl = (tt >> L) << L;          // floor boundary (local)
            const int bsl = btl + (1 << L);          // ceil boundary (local)
            const float cT  = (tt == 0) ? 0.f : ci[tt - 1];
            const float cBt = (btl == 0) ? 0.f : ci[btl - 1];
            const float cBs = ci[bsl - 1];
            sA[sw(wv * 16 + tt, ln)] = cv(r_[tt] * __expf(-(cT - cBt)));
            sB[sw(wv * 16 + tt, ln)] = cv(k_[tt] * __expf(-(cBs - ci[tt])));
        }
        f4v tmp = {0.f, 0.f, 0.f, 0.f};
        tmp = MFMA16(frag8(sA, wv * 16, 0),  frag8(sB, wv * 16, 0),  tmp);
        tmp = MFMA16(frag8(sA, wv * 16, 32), frag8(sB, wv * 16, 32), tmp);
#pragma unroll
        for (int q = 0; q < 4; ++q) {
            const int tt = (ln >> 4) * 4 + q;
            if (((tt >> L) == ((cc >> L) + 1)) && (((tt >> L) & 1) != 0))
                accD[q] += tmp[q];
        }
    }

    // ---- level 4: whole tiles (1,0),(3,2); refs = own band start/end -------
#pragma unroll
    for (int tt = 0; tt < 16; ++tt) {
        const float cT = (tt == 0) ? 0.f : ci[tt - 1];
        sA[sw(wv * 16 + tt, ln)] = cv(r_[tt] * __expf(-cT));
        sB[sw(wv * 16 + tt, ln)] = cv(k_[tt] * __expf(-(ci[15] - ci[tt])));
    }
    __syncthreads();
    f4v accL4 = {0.f, 0.f, 0.f, 0.f};
    if (wv == 1 || wv == 3) {
        accL4 = MFMA16(frag8(sA, wv * 16, 0),  frag8(sB, (wv - 1) * 16, 0),  accL4);
        accL4 = MFMA16(frag8(sA, wv * 16, 32), frag8(sB, (wv - 1) * 16, 32), accL4);
    }
    __syncthreads();   // cross-band sB reads done before L5 prep overwrites

    // ---- level 5: tiles (2,0),(2,1),(3,0),(3,1); refs at c[32] -------------
#pragma unroll
    for (int tt = 0; tt < 16; ++tt) {
        if (wv >= 2) {
            const float cT = (tt == 0) ? 0.f : ci[tt - 1];
            const float d  = (wv == 2) ? cT : (cT + sp2);
            sA[sw(wv * 16 + tt, ln)] = cv(r_[tt] * __expf(-d));
        } else {
            const float d = (wv == 0) ? (sp0 + sp1 - ci[tt]) : (sp1 - ci[tt]);
            sB[sw(wv * 16 + tt, ln)] = cv(k_[tt] * __expf(-d));
        }
    }
    __syncthreads();
    f4v acc50 = {0.f, 0.f, 0.f, 0.f}, acc51 = {0.f, 0.f, 0.f, 0.f};
    if (wv >= 2) {
        acc50 = MFMA16(frag8(sA, wv * 16, 0),  frag8(sB, 0, 0),   acc50);
        acc50 = MFMA16(frag8(sA, wv * 16, 32), frag8(sB, 0, 32),  acc50);
        acc51 = MFMA16(frag8(sA, wv * 16, 0),  frag8(sB, 16, 0),  acc51);
        acc51 = MFMA16(frag8(sA, wv * 16, 32), frag8(sB, 16, 32), acc51);
    }
    // (no barrier: R~0 prep below writes only own sA rows; L5 GEMM read own
    //  sA rows in-order and sB bands 0/1, which are not rewritten)

    // ---- R~0 (chunk-start ref) + O_inter = R~0 @ S0 (accO short-lived!) ----
#pragma unroll
    for (int tt = 0; tt < 16; ++tt) {
        const float cT = (tt == 0) ? 0.f : ci[tt - 1];
        sA[sw(wv * 16 + tt, ln)] = cv(r_[tt] * __expf(-(offW + cT)));
    }
    f4v accO[4];
#pragma unroll
    for (int jb = 0; jb < 4; ++jb) {
        f4v a = {0.f, 0.f, 0.f, 0.f};
        a = MFMA16(frag8(sA, wv * 16, 0),  frag8(sST, jb * 16, 0),  a);
        a = MFMA16(frag8(sA, wv * 16, 32), frag8(sST, jb * 16, 32), a);
        accO[jb] = a;
    }

    // ---- materialize A into sAm (=sA alias): own-band rows only, after the
    //      last own-row sA read (accO GEMM, wave-in-order) -> safe -----------
#pragma unroll
    for (int q = 0; q < 4; ++q) {
        const int tt = (ln >> 4) * 4 + q;
        sAm[sw(wv * 16 + tt, wv * 16 + cc)] = cv(accD[q]);
    }
    if (wv == 1 || wv == 3) {
#pragma unroll
        for (int q = 0; q < 4; ++q) {
            const int tt = (ln >> 4) * 4 + q;
            sAm[sw(wv * 16 + tt, (wv - 1) * 16 + cc)] = cv(accL4[q]);
        }
    }
    if (wv >= 2) {
#pragma unroll
        for (int q = 0; q < 4; ++q) {
            const int tt = (ln >> 4) * 4 + q;
            sAm[sw(wv * 16 + tt, cc)]      = cv(acc50[q]);
            sAm[sw(wv * 16 + tt, 16 + cc)] = cv(acc51[q]);
        }
    }
    if (wv == 0 || wv == 2) {    // zero upper-adjacent tile for K32 pairing
#pragma unroll
        for (int q = 0; q < 4; ++q) {
            const int tt = (ln >> 4) * 4 + q;
            sAm[sw(wv * 16 + tt, (wv + 1) * 16 + cc)] = 0;
        }
    }

    // ---- out = accO + A @ V (A-op: own rows; B-op: sVT stable since P1) ----
#pragma unroll
    for (int jb = 0; jb < 4; ++jb) {
        f4v a = accO[jb];
        a = MFMA16(frag8(sAm, wv * 16, 0), frag8(sVT, jb * 16, 0), a);
        if (wv >= 2)
            a = MFMA16(frag8(sAm, wv * 16, 32), frag8(sVT, jb * 16, 32), a);
#pragma unroll
        for (int q = 0; q < 4; ++q) {
            const int t = g * TC + wv * 16 + (ln >> 4) * 4 + q;
            out[((b * T + t) * H + h) * N + jb * 16 + (ln & 15)] = a[q];
        }
    }
}

// ---------------- K2: inter-chunk scan, in place (L -> S0), float4 ----------
__global__ __launch_bounds__(256)
void k2_scan(float* __restrict__ L, const float* __restrict__ A)
{
    const int tid = blockIdx.x * 256 + threadIdx.x;
    const int j4 = tid & (N / 4 - 1);
    const int i  = (tid >> 4) & (N - 1);
    const int bh = tid >> 10;

    float4* L4 = (float4*)L;
    const int lstride = N * N / 4;
    int lidx = bh * NG * lstride + i * (N / 4) + j4;
    int aidx = bh * NG * N + i;

    float4 S = make_float4(0.f, 0.f, 0.f, 0.f);
    for (int g = 0; g < NG; ++g) {
        const float4 l = L4[lidx];
        const float  a = A[aidx];
        L4[lidx] = S;
        S.x = fmaf(a, S.x, l.x);
        S.y = fmaf(a, S.y, l.y);
        S.z = fmaf(a, S.z, l.z);
        S.w = fmaf(a, S.w, l.w);
        lidx += lstride;
        aidx += N;
    }
}

// ---------------- no-workspace fallback: sequential per (b,h) ---------------
__global__ __launch_bounds__(64, 2)
void k_seq(const float* __restrict__ rp, const float* __restrict__ kp,
           const float* __restrict__ vp, const float* __restrict__ wp,
           const float* __restrict__ up, float* __restrict__ out)
{
    const int bh = blockIdx.x;
    const int b = bh / H, h = bh - b * H;
    const int j = threadIdx.x;

    float S[N];
#pragma unroll
    for (int i = 0; i < N; ++i) S[i] = 0.f;

    const int stride = H * N;
    int base = ((b * T) * H + h) * N;
    const int ubase = h * N;

#pragma unroll 1
    for (int tt = 0; tt < T; ++tt) {
        const float vj = vp[base + j];
        const int row = base;
        float sr = 0.f, o0 = 0.f, o1 = 0.f;
#pragma unroll
        for (int i = 0; i < N; ++i) {
            const float ki = kp[row + i];
            const float di = __expf(-__expf(wp[row + i]));
            const float ri = rp[row + i];
            sr = fmaf(ri * up[ubase + i], ki, sr);
            if (i & 1) o1 = fmaf(ri, S[i], o1);
            else       o0 = fmaf(ri, S[i], o0);
            S[i] = fmaf(di, S[i], ki * vj);
        }
        out[base + j] = fmaf(sr, vj, o0 + o1);
        base += stride;
    }
}

} // anon namespace

extern "C" void kernel_launch(void* const* d_in, const int* in_sizes, int n_in,
                              void* d_out, int out_size, void* d_ws, size_t ws_size,
                              hipStream_t stream)
{
    const float* r = (const float*)d_in[0];
    const float* k = (const float*)d_in[1];
    const float* v = (const float*)d_in[2];
    const float* w = (const float*)d_in[3];
    const float* u = (const float*)d_in[4];
    float* out = (float*)d_out;

    const size_t l_elems = (size_t)BH * NG * N * N;   // 8,388,608
    const size_t a_elems = (size_t)BH * NG * N;       // 131,072
    const size_t ws_need = (l_elems + a_elems) * sizeof(float);  // ~34 MB

    if (ws_size >= ws_need) {
        float* L = (float*)d_ws;
        float* A = L + l_elems;
        k13<0><<<BH * NG, 256, 0, stream>>>(r, k, v, w, u, nullptr, L, A, nullptr);
        k2_scan<<<(BH * N * N / 4) / 256, 256, 0, stream>>>(L, A);
        k13<1><<<BH * NG, 256, 0, stream>>>(r, k, v, w, u, L, nullptr, nullptr, out);
    } else {
        k_seq<<<BH, 64, 0, stream>>>(r, k, v, w, u, out);
    }
}